// Round 5
// baseline (229.482 us; speedup 1.0000x reference)
//
#include <hip/hip_runtime.h>
#include <hip/hip_bf16.h>
#include <math.h>

// Problem shape (fixed): x [B,T,D] fp32, log_alpha scalar fp32, out [B,T,D] fp32.
#define B_ 4
#define T_ 4096
#define D_ 512
#define BT 128                 // t/s tile size per block (128x128 pair)
#define NT (T_ / BT)           // 32 tiles per batch
#define NPAIR (NT * (NT + 1) / 2)  // 528 lower-triangle tile pairs

// Workspace layout (needs 64 KiB + 16 MiB):
//   [0 .. 64KiB)                maxsim as order-preserving uint32 [B*T]
//   [64KiB .. 64KiB+B*T*D*2)    xn: normalized rows, bf16 bits (ushort)

typedef short bf16x8 __attribute__((ext_vector_type(8)));
typedef float f32x4 __attribute__((ext_vector_type(4)));

__device__ __forceinline__ unsigned short f2bf(float f) {
    unsigned u = __float_as_uint(f);
    u += 0x7FFFu + ((u >> 16) & 1u);   // RNE
    return (unsigned short)(u >> 16);
}
// monotone float -> uint so unsigned atomicMax orders like float
__device__ __forceinline__ unsigned f2ord(float f) {
    unsigned u = __float_as_uint(f);
    return (u & 0x80000000u) ? ~u : (u | 0x80000000u);
}
__device__ __forceinline__ float ord2f(unsigned u) {
    unsigned b = (u & 0x80000000u) ? (u ^ 0x80000000u) : ~u;
    return __uint_as_float(b);
}

// ---- Kernel 1: one wave per row. inv-norm + bf16 row write + maxsim init ----
__global__ __launch_bounds__(256) void k_norm(const float* __restrict__ x,
                                              unsigned short* __restrict__ xn,
                                              unsigned* __restrict__ maxsim) {
    int w = (blockIdx.x * 256 + threadIdx.x) >> 6;   // row id (B*T rows)
    int lane = threadIdx.x & 63;
    const float4* xr = (const float4*)(x + (size_t)w * D_);
    float4 a = xr[lane];          // lane-contiguous: full coalescing
    float4 b = xr[lane + 64];
    float ss = a.x * a.x + a.y * a.y + a.z * a.z + a.w * a.w +
               b.x * b.x + b.y * b.y + b.z * b.z + b.w * b.w;
#pragma unroll
    for (int off = 32; off > 0; off >>= 1) ss += __shfl_xor(ss, off);
    float inv = 1.0f / fmaxf(sqrtf(ss), 1e-12f);
    unsigned u0 = (unsigned)f2bf(a.x * inv) | ((unsigned)f2bf(a.y * inv) << 16);
    unsigned u1 = (unsigned)f2bf(a.z * inv) | ((unsigned)f2bf(a.w * inv) << 16);
    unsigned u2 = (unsigned)f2bf(b.x * inv) | ((unsigned)f2bf(b.y * inv) << 16);
    unsigned u3 = (unsigned)f2bf(b.z * inv) | ((unsigned)f2bf(b.w * inv) << 16);
    uint2* xo = (uint2*)(xn + (size_t)w * D_);
    xo[lane]      = make_uint2(u0, u1);
    xo[lane + 64] = make_uint2(u2, u3);
    if (lane == 0) maxsim[w] = f2ord(-2.0f);
}

// ---- Kernel 2: one block per (t-tile, s-tile) pair — NO LDS, NO BARRIERS ----
// MFMA A/B fragments for 16x16x32 are contiguous 16B row-chunks of xn
// (A[m=lane&15][k=(lane>>4)*8+j], B likewise for B^T-style row operand —
// identical per-lane elements to what the R1-R4 LDS path delivered).
// Load them straight from global; reuse comes from L1 (intra-block: wave
// pairs read identical addresses) and L2/LLC (xn per batch = 4 MB ~ one
// XCD L2). Depth-1 prefetch => compiler emits vmcnt(8)-style waits, never
// a full drain; waves are fully decorrelated (zero barriers).
__global__ __launch_bounds__(256) void k_maxsim(const unsigned short* __restrict__ xn,
                                                unsigned* __restrict__ maxsim) {
    const int b = blockIdx.y;
    const int p = blockIdx.x;
    // triangular decode p -> (ti, si), si <= ti
    int ti = (int)((sqrtf(8.0f * (float)p + 1.0f) - 1.0f) * 0.5f);
    while ((ti + 1) * (ti + 2) / 2 <= p) ti++;
    while (ti * (ti + 1) / 2 > p) ti--;
    const int si = p - ti * (ti + 1) / 2;
    const int t0 = ti * BT, s0 = si * BT;

    const int tid = threadIdx.x;
    const int wave = tid >> 6, lane = tid & 63;
    const int wm = wave >> 1, wn = wave & 1;     // 2x2 waves -> 64x64 each
    const int qa = lane >> 4, la = lane & 15;

    // per-lane fragment base pointers (frag i adds i*16 rows; step adds k)
    const unsigned short* pa = xn + (size_t)(b * T_ + t0 + wm * 64 + la) * D_ + qa * 8;
    const unsigned short* pb = xn + (size_t)(b * T_ + s0 + wn * 64 + la) * D_ + qa * 8;

    f32x4 acc[4][4];
#pragma unroll
    for (int i = 0; i < 4; i++)
#pragma unroll
        for (int j = 0; j < 4; j++) acc[i][j] = (f32x4){0.f, 0.f, 0.f, 0.f};

    bf16x8 sa[2][4], sb[2][4];
    // prologue: load step 0 fragments
#pragma unroll
    for (int i = 0; i < 4; i++) sa[0][i] = *(const bf16x8*)(pa + (size_t)i * 16 * D_);
#pragma unroll
    for (int j = 0; j < 4; j++) sb[0][j] = *(const bf16x8*)(pb + (size_t)j * 16 * D_);

#pragma unroll 2
    for (int k = 0; k < 16; ++k) {
        const int cur = k & 1, nxt = cur ^ 1;
        if (k < 15) {   // prefetch step k+1 while step k computes
            const int ko = (k + 1) * 32;
#pragma unroll
            for (int i = 0; i < 4; i++)
                sa[nxt][i] = *(const bf16x8*)(pa + (size_t)i * 16 * D_ + ko);
#pragma unroll
            for (int j = 0; j < 4; j++)
                sb[nxt][j] = *(const bf16x8*)(pb + (size_t)j * 16 * D_ + ko);
        }
#pragma unroll
        for (int i = 0; i < 4; i++)
#pragma unroll
            for (int j = 0; j < 4; j++)
                acc[i][j] = __builtin_amdgcn_mfma_f32_16x16x32_bf16(sa[cur][i], sb[cur][j], acc[i][j], 0, 0, 0);
    }

    // epilogue: per-row max over this tile's s-columns, then global atomicMax.
    // C/D layout (verified): col = lane&15, row = (lane>>4)*4 + reg
    const bool diag = (ti == si);
#pragma unroll
    for (int i = 0; i < 4; i++) {
#pragma unroll
        for (int r = 0; r < 4; r++) {
            int tl = wm * 64 + i * 16 + qa * 4 + r;   // local t row
            float m = -2.0f;
#pragma unroll
            for (int j = 0; j < 4; j++) {
                int sl = wn * 64 + j * 16 + la;       // local s col
                float v = acc[i][j][r];
                if (!diag || sl < tl) m = fmaxf(m, v);
            }
#pragma unroll
            for (int off = 1; off < 16; off <<= 1) m = fmaxf(m, __shfl_xor(m, off));
            if (la == 0) atomicMax(&maxsim[b * T_ + t0 + tl], f2ord(m));
        }
    }
}

// ---- Kernel 3: gate + tanh-GELU, one float4 per thread ----
__device__ __forceinline__ float gelu_tanh(float y) {
    float t = tanhf(0.7978845608028654f * (y + 0.044715f * y * y * y));
    return 0.5f * y * (1.0f + t);
}

__global__ __launch_bounds__(256) void k_gate(const float* __restrict__ x,
                                              const float* __restrict__ log_alpha,
                                              const unsigned* __restrict__ maxsim,
                                              float* __restrict__ out) {
    int idx = blockIdx.x * 256 + threadIdx.x;     // one float4 per thread
    float la = log_alpha[0];
    float alpha = (la > 20.0f) ? la : log1pf(expf(la));
    int row = idx >> 7;                           // 128 float4-threads per row
    float m = fmaxf(ord2f(maxsim[row]), -1.0f);
    float novelty = 1.0f - (m + 1.0f) * 0.5f;
    float gate = 1.0f + alpha * novelty;
    float4 v = ((const float4*)x)[idx];
    float4 o;
    o.x = gelu_tanh(v.x * gate);
    o.y = gelu_tanh(v.y * gate);
    o.z = gelu_tanh(v.z * gate);
    o.w = gelu_tanh(v.w * gate);
    ((float4*)out)[idx] = o;
}

extern "C" void kernel_launch(void* const* d_in, const int* in_sizes, int n_in,
                              void* d_out, int out_size, void* d_ws, size_t ws_size,
                              hipStream_t stream) {
    const float* x = (const float*)d_in[0];
    const float* log_alpha = (const float*)d_in[1];
    float* out = (float*)d_out;

    unsigned* maxsim = (unsigned*)d_ws;
    unsigned short* xn = (unsigned short*)((char*)d_ws + 65536);

    const int rows = B_ * T_;                     // 16384
    k_norm<<<rows / 4, 256, 0, stream>>>(x, xn, maxsim);

    dim3 g2(NPAIR, B_);
    k_maxsim<<<g2, 256, 0, stream>>>(xn, maxsim);

    k_gate<<<(B_ * T_ * D_ / 4) / 256, 256, 0, stream>>>(x, log_alpha, maxsim, out);
}

// Round 6
// 144.193 us; speedup vs baseline: 1.5915x; 1.5915x over previous
//
#include <hip/hip_runtime.h>
#include <hip/hip_bf16.h>
#include <math.h>

// Problem shape (fixed): x [B,T,D] fp32, log_alpha scalar fp32, out [B,T,D] fp32.
#define B_ 4
#define T_ 4096
#define D_ 512
#define BT 128                 // t/s tile size per block (128x128 pair)
#define BK 32                  // K per pipeline step
#define STEPS (D_ / BK)        // 16
#define NT (T_ / BT)           // 32 tiles per batch
#define NPAIR (NT * (NT + 1) / 2)  // 528 lower-triangle tile pairs

// Workspace layout (needs 64 KiB + 16 MiB):
//   [0 .. 64KiB)                maxsim as order-preserving uint32 [B*T]
//   [64KiB .. 64KiB+B*T*D*2)    xn: normalized rows, bf16 bits (ushort)

typedef short bf16x8 __attribute__((ext_vector_type(8)));
typedef float f32x4 __attribute__((ext_vector_type(4)));

__device__ __forceinline__ unsigned short f2bf(float f) {
    unsigned u = __float_as_uint(f);
    u += 0x7FFFu + ((u >> 16) & 1u);   // RNE
    return (unsigned short)(u >> 16);
}
// monotone float -> uint so unsigned atomicMax orders like float
__device__ __forceinline__ unsigned f2ord(float f) {
    unsigned u = __float_as_uint(f);
    return (u & 0x80000000u) ? ~u : (u | 0x80000000u);
}
__device__ __forceinline__ float ord2f(unsigned u) {
    unsigned b = (u & 0x80000000u) ? (u ^ 0x80000000u) : ~u;
    return __uint_as_float(b);
}

__device__ __forceinline__ void async16(const unsigned short* g, unsigned short* l) {
    // 16B/lane global->LDS DMA; LDS dest = wave-uniform base + lane*16
    __builtin_amdgcn_global_load_lds(
        (const __attribute__((address_space(1))) unsigned int*)g,
        (__attribute__((address_space(3))) unsigned int*)l, 16, 0, 0);
}

// ---- Kernel 1: one wave per row. inv-norm + bf16 row write + maxsim init ----
__global__ __launch_bounds__(256) void k_norm(const float* __restrict__ x,
                                              unsigned short* __restrict__ xn,
                                              unsigned* __restrict__ maxsim) {
    int w = (blockIdx.x * 256 + threadIdx.x) >> 6;   // row id (B*T rows)
    int lane = threadIdx.x & 63;
    const float4* xr = (const float4*)(x + (size_t)w * D_);
    float4 a = xr[lane];          // lane-contiguous: full coalescing
    float4 b = xr[lane + 64];
    float ss = a.x * a.x + a.y * a.y + a.z * a.z + a.w * a.w +
               b.x * b.x + b.y * b.y + b.z * b.z + b.w * b.w;
#pragma unroll
    for (int off = 32; off > 0; off >>= 1) ss += __shfl_xor(ss, off);
    float inv = 1.0f / fmaxf(sqrtf(ss), 1e-12f);
    unsigned u0 = (unsigned)f2bf(a.x * inv) | ((unsigned)f2bf(a.y * inv) << 16);
    unsigned u1 = (unsigned)f2bf(a.z * inv) | ((unsigned)f2bf(a.w * inv) << 16);
    unsigned u2 = (unsigned)f2bf(b.x * inv) | ((unsigned)f2bf(b.y * inv) << 16);
    unsigned u3 = (unsigned)f2bf(b.z * inv) | ((unsigned)f2bf(b.w * inv) << 16);
    uint2* xo = (uint2*)(xn + (size_t)w * D_);
    xo[lane]      = make_uint2(u0, u1);
    xo[lane + 64] = make_uint2(u2, u3);
    if (lane == 0) maxsim[w] = f2ord(-2.0f);
}

// ---- Kernel 2: one block per (t-tile, s-tile) pair ----
// 3-stage circular DMA pipeline, ONE raw s_barrier per K-step, fine vmcnt:
//   step k: wait vmcnt(4)   -> drains step-k DMAs (issued 2 steps ago, ~free;
//                              step-k+1's 4 stay in flight)
//           s_barrier        -> NO vmcnt drain (the R1 structural stall)
//           issue DMA k+2    -> into buffer last read at k-1 (readers provably
//                              done: their lgkm waits preceded their MFMAs,
//                              which preceded this barrier)
//           ds_read + 16 MFMA on buf[k%3]
// XOR swizzle (R2-measured ZERO conflicts): LDS chunk c holds global chunk
// (c&3)^((row>>1)&3) of row c>>2; reader uses qa^((la>>1)&3).
// NOTE: plain launch_bounds(256) — (256,4) spilled in R2. Do not re-add.
__global__ __launch_bounds__(256) void k_maxsim(const unsigned short* __restrict__ xn,
                                                unsigned* __restrict__ maxsim) {
    __shared__ __align__(16) unsigned short Buf[3][8192];   // per stage: A[0..4095], B[4096..8191]
    const int b = blockIdx.y;
    const int p = blockIdx.x;
    // triangular decode p -> (ti, si), si <= ti
    int ti = (int)((sqrtf(8.0f * (float)p + 1.0f) - 1.0f) * 0.5f);
    while ((ti + 1) * (ti + 2) / 2 <= p) ti++;
    while (ti * (ti + 1) / 2 > p) ti--;
    const int si = p - ti * (ti + 1) / 2;
    const int t0 = ti * BT, s0 = si * BT;

    const int tid = threadIdx.x;
    const int wave = tid >> 6, lane = tid & 63;
    const int wm = wave >> 1, wn = wave & 1;     // 2x2 waves -> 64x64 each
    const int qa = lane >> 4, la = lane & 15;
    const int swz = (la >> 1) & 3;               // read-side row-phase XOR

    const unsigned short* Ab = xn + (size_t)(b * T_ + t0) * D_;
    const unsigned short* Bb = xn + (size_t)(b * T_ + s0) * D_;

    // DMA staging addresses (R1 pattern + R2 swizzle), hoisted:
    // j in {0,1}: chunk c = j*256+tid; row=c>>2; swizzled global chunk
    const int c0 = tid,        r0_ = c0 >> 2, g0 = (c0 & 3) ^ ((r0_ >> 1) & 3);
    const int c1 = 256 + tid,  r1_ = c1 >> 2, g1 = (c1 & 3) ^ ((r1_ >> 1) & 3);
    const unsigned short* gA0 = Ab + (size_t)r0_ * D_ + g0 * 8;
    const unsigned short* gA1 = Ab + (size_t)r1_ * D_ + g1 * 8;
    const unsigned short* gB0 = Bb + (size_t)r0_ * D_ + g0 * 8;
    const unsigned short* gB1 = Bb + (size_t)r1_ * D_ + g1 * 8;
    const int ldsb0 = (wave * 64) * 8;           // wave-uniform chunk base, j=0
    const int ldsb1 = (256 + wave * 64) * 8;     // j=1

#define STAGE(step, st)                                            \
    do {                                                           \
        async16(gA0 + (step) * BK, &Buf[st][ldsb0]);               \
        async16(gB0 + (step) * BK, &Buf[st][4096 + ldsb0]);        \
        async16(gA1 + (step) * BK, &Buf[st][ldsb1]);               \
        async16(gB1 + (step) * BK, &Buf[st][4096 + ldsb1]);        \
    } while (0)

    f32x4 acc[4][4];
#pragma unroll
    for (int i = 0; i < 4; i++)
#pragma unroll
        for (int j = 0; j < 4; j++) acc[i][j] = (f32x4){0.f, 0.f, 0.f, 0.f};

    // prologue: steps 0 and 1 in flight (4 DMA instrs each, per wave)
    STAGE(0, 0);
    STAGE(1, 1);

#pragma unroll
    for (int k = 0; k < STEPS; ++k) {
        const int cur = k % 3;
        // simm16: vmcnt lo[3:0] | expcnt(7)<<4 | lgkmcnt(15)<<8 | vmcnt hi<<14
        if (k == STEPS - 1) __builtin_amdgcn_s_waitcnt(0x0F70);  // vmcnt(0)
        else                __builtin_amdgcn_s_waitcnt(0x0F74);  // vmcnt(4)
        __builtin_amdgcn_s_barrier();
        __asm__ __volatile__("" ::: "memory");   // pin LDS reads below barrier
        if (k + 2 < STEPS) STAGE(k + 2, (k + 2) % 3);

        const unsigned short* As = &Buf[cur][0];
        const unsigned short* Bs = &Buf[cur][4096];
        bf16x8 af[4], bfr[4];
#pragma unroll
        for (int i = 0; i < 4; i++)
            af[i] = *(const bf16x8*)&As[(wm * 64 + i * 16 + la) * BK + (qa ^ swz) * 8];
#pragma unroll
        for (int j = 0; j < 4; j++)
            bfr[j] = *(const bf16x8*)&Bs[(wn * 64 + j * 16 + la) * BK + (qa ^ swz) * 8];
#pragma unroll
        for (int i = 0; i < 4; i++)
#pragma unroll
            for (int j = 0; j < 4; j++)
                acc[i][j] = __builtin_amdgcn_mfma_f32_16x16x32_bf16(af[i], bfr[j], acc[i][j], 0, 0, 0);
    }
#undef STAGE

    // epilogue: per-row max over this tile's s-columns, then global atomicMax.
    // C/D layout (verified): col = lane&15, row = (lane>>4)*4 + reg
    const bool diag = (ti == si);
#pragma unroll
    for (int i = 0; i < 4; i++) {
#pragma unroll
        for (int r = 0; r < 4; r++) {
            int tl = wm * 64 + i * 16 + qa * 4 + r;   // local t row
            float m = -2.0f;
#pragma unroll
            for (int j = 0; j < 4; j++) {
                int sl = wn * 64 + j * 16 + la;       // local s col
                float v = acc[i][j][r];
                if (!diag || sl < tl) m = fmaxf(m, v);
            }
#pragma unroll
            for (int off = 1; off < 16; off <<= 1) m = fmaxf(m, __shfl_xor(m, off));
            if (la == 0) atomicMax(&maxsim[b * T_ + t0 + tl], f2ord(m));
        }
    }
}

// ---- Kernel 3: gate + tanh-GELU, one float4 per thread ----
__device__ __forceinline__ float gelu_tanh(float y) {
    float t = tanhf(0.7978845608028654f * (y + 0.044715f * y * y * y));
    return 0.5f * y * (1.0f + t);
}

__global__ __launch_bounds__(256) void k_gate(const float* __restrict__ x,
                                              const float* __restrict__ log_alpha,
                                              const unsigned* __restrict__ maxsim,
                                              float* __restrict__ out) {
    int idx = blockIdx.x * 256 + threadIdx.x;     // one float4 per thread
    float la = log_alpha[0];
    float alpha = (la > 20.0f) ? la : log1pf(expf(la));
    int row = idx >> 7;                           // 128 float4-threads per row
    float m = fmaxf(ord2f(maxsim[row]), -1.0f);
    float novelty = 1.0f - (m + 1.0f) * 0.5f;
    float gate = 1.0f + alpha * novelty;
    float4 v = ((const float4*)x)[idx];
    float4 o;
    o.x = gelu_tanh(v.x * gate);
    o.y = gelu_tanh(v.y * gate);
    o.z = gelu_tanh(v.z * gate);
    o.w = gelu_tanh(v.w * gate);
    ((float4*)out)[idx] = o;
}

extern "C" void kernel_launch(void* const* d_in, const int* in_sizes, int n_in,
                              void* d_out, int out_size, void* d_ws, size_t ws_size,
                              hipStream_t stream) {
    const float* x = (const float*)d_in[0];
    const float* log_alpha = (const float*)d_in[1];
    float* out = (float*)d_out;

    unsigned* maxsim = (unsigned*)d_ws;
    unsigned short* xn = (unsigned short*)((char*)d_ws + 65536);

    const int rows = B_ * T_;                     // 16384
    k_norm<<<rows / 4, 256, 0, stream>>>(x, xn, maxsim);

    dim3 g2(NPAIR, B_);
    k_maxsim<<<g2, 256, 0, stream>>>(xn, maxsim);

    k_gate<<<(B_ * T_ * D_ / 4) / 256, 256, 0, stream>>>(x, log_alpha, maxsim, out);
}